// Round 5
// baseline (468.531 us; speedup 1.0000x reference)
//
#include <hip/hip_runtime.h>

#define H 32
#define PITCH 40   // floats per h-slot (160 B): 16B-aligned slots, <=2-way bank alias (free)

// tanh(x) = 1 - 2/(1 + exp2(x * 2*log2(e))); saturates correctly at +/-inf.
__device__ __forceinline__ float fast_tanh(float x) {
    float e = __builtin_amdgcn_exp2f(x * 2.8853900817779268f);
    float r = __builtin_amdgcn_rcpf(e + 1.0f);
    return fmaf(-2.0f, r, 1.0f);
}

// acc += (quad-lane q's copy of p) * w — one v_fmac_f32_dpp.
// DPP-routed src0 (p) is only ever a ds_read destination => no VALU->DPP hazard.
#define QFMA(acc, p, w, q) \
    asm("v_fmac_f32_dpp %0, %1, %2 quad_perm:[" #q "," #q "," #q "," #q "] row_mask:0xf bank_mask:0xf" \
        : "+v"(acc) : "v"(p), "v"(w))

#define CH8(acc, q) \
    QFMA(acc, pN[0], whh[8*q+0], q); QFMA(acc, pN[1], whh[8*q+1], q); \
    QFMA(acc, pN[2], whh[8*q+2], q); QFMA(acc, pN[3], whh[8*q+3], q); \
    QFMA(acc, pN[4], whh[8*q+4], q); QFMA(acc, pN[5], whh[8*q+5], q); \
    QFMA(acc, pN[6], whh[8*q+6], q); QFMA(acc, pN[7], whh[8*q+7], q)

// dpp mov, bound_ctrl=1: shifted-in lanes contribute 0 (builtin => compiler
// inserts the required DPP hazard nops itself).
#define DPPMOV(x, ctrl) \
    __int_as_float(__builtin_amdgcn_update_dpp(0, __float_as_int(x), (ctrl), 0xf, 0xf, true))
#define ROW_SHR1 0x111
#define ROW_SHR2 0x112
#define ROW_SHR4 0x114

__global__ __launch_bounds__(64, 1) void rnn_fused(
    const float* __restrict__ onehot,   // [B,T,4]
    const float* __restrict__ rewards,  // [B,T]
    const float* __restrict__ W_ih,     // [H,5]
    const float* __restrict__ W_hh,     // [H,H]
    const float* __restrict__ b_ih,     // [H]
    const float* __restrict__ b_hh,     // [H]
    const float* __restrict__ W_ro,     // [4,H]
    const float* __restrict__ b_ro,     // [4]
    float* __restrict__ out_logits,     // [B,T,4]
    float* __restrict__ out_hT,         // [B,H]
    int T)
{
    const int tid = threadIdx.x;
    const int u  = tid & 31;             // hidden unit owned by this lane
    const int g  = tid >> 5;             // 32-lane group within the wave
    const int qp = u & 3;                // quad position -> which 8-chunk we gather
    const int r  = u >> 3;               // readout row this lane contributes to
    const bool hi = ((u >> 2) & 1) != 0; // which half of the chunk for readout
    const bool writer = (u & 7) == 7;    // lane that stores logit row r

    // Two chains (batch elements) per group, staggered in time.
    const int b0 = blockIdx.x * 4 + g * 2;
    const int b1 = b0 + 1;

    __shared__ __align__(16) float hx[4 * PITCH];
    float* wr0 = &hx[(2 * g + 0) * PITCH + u];
    float* wr1 = &hx[(2 * g + 1) * PITCH + u];
    const float4* rd0 = (const float4*)&hx[(2 * g + 0) * PITCH + qp * 8];
    const float4* rd1 = (const float4*)&hx[(2 * g + 1) * PITCH + qp * 8];

    // ---- per-lane weights (shared by both chains) ----
    float whh[H];
#pragma unroll
    for (int k = 0; k < 8; ++k) {
        float4 w = *(const float4*)(W_hh + u * H + 4 * k);
        whh[4*k+0] = w.x; whh[4*k+1] = w.y; whh[4*k+2] = w.z; whh[4*k+3] = w.w;
    }
    const float wih0 = W_ih[u*5+0], wih1 = W_ih[u*5+1], wih2 = W_ih[u*5+2],
                wih3 = W_ih[u*5+3], wih4 = W_ih[u*5+4];
    const float bias = b_ih[u] + b_hh[u];
    const float4 wr4 = *(const float4*)(W_ro + r * H + qp * 8 + (hi ? 4 : 0));
    const float bro = b_ro[r];

    const float* ohp0 = onehot  + (size_t)b0 * T * 4;
    const float* ohp1 = onehot  + (size_t)b1 * T * 4;
    const float* rwp0 = rewards + (size_t)b0 * T;
    const float* rwp1 = rewards + (size_t)b1 * T;
    float*       lgp0 = out_logits + (size_t)b0 * T * 4;
    float*       lgp1 = out_logits + (size_t)b1 * T * 4;

    // ---- 4-step x prefetch rings, one per chain ----
    float4 A0 = *(const float4*)(ohp0 + 0), A1 = *(const float4*)(ohp0 + 4);
    float4 A2 = *(const float4*)(ohp0 + 8), A3 = *(const float4*)(ohp0 + 12);
    float4 Ar = *(const float4*)(rwp0);
    float4 B0 = *(const float4*)(ohp1 + 0), B1 = *(const float4*)(ohp1 + 4);
    float4 B2 = *(const float4*)(ohp1 + 8), B3 = *(const float4*)(ohp1 + 12);
    float4 Br = *(const float4*)(rwp1);

    float h0 = 0.0f, h1 = 0.0f;          // h^{(-1)} = 0
    float4 v00, v01, v10, v11;           // in-flight gathered reads per chain

    // logits_{t} for one chain from its gathered h^{(t)} chunk
    auto readout_store = [&](const float (&p)[8], float* lgp, int t) {
        float s0 = hi ? p[4] : p[0];
        float s1 = hi ? p[5] : p[1];
        float s2 = hi ? p[6] : p[2];
        float s3 = hi ? p[7] : p[3];
        float s = fmaf(s3, wr4.w, fmaf(s2, wr4.z, fmaf(s1, wr4.y, s0 * wr4.x)));
        s += DPPMOV(s, ROW_SHR1);
        s += DPPMOV(s, ROW_SHR2);
        s += DPPMOV(s, ROW_SHR4);        // lane (8r+7) holds full dot of row r
        if (writer) lgp[(size_t)t * 4 + r] = s + bro;
    };

    // compute h^{(t)} for one chain from the in-flight gather of h^{(t-1)};
    // emits logits_{t-1} first (uses same gather; fills the lgkm wait window).
    auto compute = [&](float4 v0, float4 v1, float xp, float* lgp, int tm1,
                       bool ro) -> float {
        float pN[8] = {v0.x, v0.y, v0.z, v0.w, v1.x, v1.y, v1.z, v1.w};
        if (ro) readout_store(pN, lgp, tm1);
        float a0 = xp, a1 = 0.f, a2 = 0.f, a3 = 0.f;
        CH8(a0, 0);
        CH8(a1, 1);
        CH8(a2, 2);
        CH8(a3, 3);
        return fast_tanh((a0 + a1) + (a2 + a3));
    };

#define PUBLISH0(h) { *wr0 = (h); v00 = rd0[0]; v01 = rd0[1]; }
#define PUBLISH1(h) { *wr1 = (h); v10 = rd1[0]; v11 = rd1[1]; }

// One staggered timestep: c0's gather latency was covered by the previous
// c1 compute; c1's gather latency is covered by c0's compute here.
#define STEP(xpA, xpB, tm1, ro) { \
    h0 = compute(v00, v01, (xpA), lgp0, (tm1), (ro)); PUBLISH0(h0); \
    h1 = compute(v10, v11, (xpB), lgp1, (tm1), (ro)); PUBLISH1(h1); }

#define XP(oh, rwc) fmaf((oh).x, wih0, fmaf((oh).y, wih1, fmaf((oh).z, wih2, \
                     fmaf((oh).w, wih3, fmaf((rwc), wih4, bias)))))

    // prologue: publish h^{(-1)} = 0 for both chains (issues first gathers)
    PUBLISH0(0.0f);
    PUBLISH1(0.0f);

    // ---- first block (t = 0..3): no logits for t-1 = -1 ----
    {
        float xA0 = XP(A0, Ar.x), xA1 = XP(A1, Ar.y), xA2 = XP(A2, Ar.z), xA3 = XP(A3, Ar.w);
        float xB0 = XP(B0, Br.x), xB1 = XP(B1, Br.y), xB2 = XP(B2, Br.z), xB3 = XP(B3, Br.w);
        A0 = *(const float4*)(ohp0 + 16); A1 = *(const float4*)(ohp0 + 20);
        A2 = *(const float4*)(ohp0 + 24); A3 = *(const float4*)(ohp0 + 28);
        Ar = *(const float4*)(rwp0 + 4);
        B0 = *(const float4*)(ohp1 + 16); B1 = *(const float4*)(ohp1 + 20);
        B2 = *(const float4*)(ohp1 + 24); B3 = *(const float4*)(ohp1 + 28);
        Br = *(const float4*)(rwp1 + 4);
        STEP(xA0, xB0, -1, false);
        STEP(xA1, xB1,  0, true);
        STEP(xA2, xB2,  1, true);
        STEP(xA3, xB3,  2, true);
    }

    for (int tb = 4; tb < T; tb += 4) {
        float xA0 = XP(A0, Ar.x), xA1 = XP(A1, Ar.y), xA2 = XP(A2, Ar.z), xA3 = XP(A3, Ar.w);
        float xB0 = XP(B0, Br.x), xB1 = XP(B1, Br.y), xB2 = XP(B2, Br.z), xB3 = XP(B3, Br.w);
        if (tb + 4 < T) {
            A0 = *(const float4*)(ohp0 + (size_t)(tb + 4) * 4);
            A1 = *(const float4*)(ohp0 + (size_t)(tb + 5) * 4);
            A2 = *(const float4*)(ohp0 + (size_t)(tb + 6) * 4);
            A3 = *(const float4*)(ohp0 + (size_t)(tb + 7) * 4);
            Ar = *(const float4*)(rwp0 + tb + 4);
            B0 = *(const float4*)(ohp1 + (size_t)(tb + 4) * 4);
            B1 = *(const float4*)(ohp1 + (size_t)(tb + 5) * 4);
            B2 = *(const float4*)(ohp1 + (size_t)(tb + 6) * 4);
            B3 = *(const float4*)(ohp1 + (size_t)(tb + 7) * 4);
            Br = *(const float4*)(rwp1 + tb + 4);
        }
        STEP(xA0, xB0, tb - 1, true);
        STEP(xA1, xB1, tb + 0, true);
        STEP(xA2, xB2, tb + 1, true);
        STEP(xA3, xB3, tb + 2, true);
    }

    // ---- epilogue: logits_{T-1} from the final gathers (= h^{(T-1)}) ----
    {
        float pN[8] = {v00.x, v00.y, v00.z, v00.w, v01.x, v01.y, v01.z, v01.w};
        readout_store(pN, lgp0, T - 1);
    }
    {
        float pN[8] = {v10.x, v10.y, v10.z, v10.w, v11.x, v11.y, v11.z, v11.w};
        readout_store(pN, lgp1, T - 1);
    }
    out_hT[(size_t)b0 * H + u] = h0;     // h_T
    out_hT[(size_t)b1 * H + u] = h1;
}

extern "C" void kernel_launch(void* const* d_in, const int* in_sizes, int n_in,
                              void* d_out, int out_size, void* d_ws, size_t ws_size,
                              hipStream_t stream) {
    const float* onehot  = (const float*)d_in[0];
    const float* rewards = (const float*)d_in[1];
    const float* W_ih    = (const float*)d_in[2];
    const float* W_hh    = (const float*)d_in[3];
    const float* b_ih    = (const float*)d_in[4];
    const float* b_hh    = (const float*)d_in[5];
    const float* W_ro    = (const float*)d_in[6];
    const float* b_ro    = (const float*)d_in[7];

    const int T = 1024;                  // per setup_inputs()
    const int B = in_sizes[1] / T;       // in_sizes[1] = B*T

    float* out_logits = (float*)d_out;                        // [B,T,4]
    float* out_hT     = (float*)d_out + (size_t)B * T * 4;    // [B,H]

    dim3 block(64);                      // 1 wave = 2 groups x 2 staggered chains
    dim3 grid(B / 4);                    // 512 blocks -> 2 waves/CU, SIMDs spread
    rnn_fused<<<grid, block, 0, stream>>>(onehot, rewards, W_ih, W_hh,
                                          b_ih, b_hh, W_ro, b_ro,
                                          out_logits, out_hT, T);
}

// Round 6
// 314.894 us; speedup vs baseline: 1.4879x; 1.4879x over previous
//
#include <hip/hip_runtime.h>

#define H 32
#define GPB 8   // 32-lane groups per 256-thread block

// tanh(x) = 1 - 2/(1 + exp2(x * 2*log2(e))); saturates correctly at +/-inf.
__device__ __forceinline__ float fast_tanh(float x) {
    float e = __builtin_amdgcn_exp2f(x * 2.8853900817779268f);
    float r = __builtin_amdgcn_rcpf(e + 1.0f);
    return fmaf(-2.0f, r, 1.0f);
}

// acc += (quad-lane q's copy of p) * w — one v_fmac_f32_dpp.
// p regs are only written by ds_bpermute (lgkmcnt-guarded) => no VALU->DPP hazard.
#define QFMA(acc, p, w, q) \
    asm("v_fmac_f32_dpp %0, %1, %2 quad_perm:[" #q "," #q "," #q "," #q "] row_mask:0xf bank_mask:0xf" \
        : "+v"(acc) : "v"(p), "v"(w))

#define CH8(acc, q) \
    QFMA(acc, pN[0], whh[8*q+0], q); QFMA(acc, pN[1], whh[8*q+1], q); \
    QFMA(acc, pN[2], whh[8*q+2], q); QFMA(acc, pN[3], whh[8*q+3], q); \
    QFMA(acc, pN[4], whh[8*q+4], q); QFMA(acc, pN[5], whh[8*q+5], q); \
    QFMA(acc, pN[6], whh[8*q+6], q); QFMA(acc, pN[7], whh[8*q+7], q)

// dpp mov, bound_ctrl=1: shifted-in lanes contribute 0 (builtin => compiler
// inserts any required hazard nops itself).
#define DPPMOV(x, ctrl) \
    __int_as_float(__builtin_amdgcn_update_dpp(0, __float_as_int(x), (ctrl), 0xf, 0xf, true))
#define ROW_SHR1 0x111
#define ROW_SHR2 0x112
#define ROW_SHR4 0x114

__global__ __launch_bounds__(256, 1) void rnn_fused(
    const float* __restrict__ onehot,   // [B,T,4]
    const float* __restrict__ rewards,  // [B,T]
    const float* __restrict__ W_ih,     // [H,5]
    const float* __restrict__ W_hh,     // [H,H]
    const float* __restrict__ b_ih,     // [H]
    const float* __restrict__ b_hh,     // [H]
    const float* __restrict__ W_ro,     // [4,H]
    const float* __restrict__ b_ro,     // [4]
    float* __restrict__ out_logits,     // [B,T,4]
    float* __restrict__ out_hT,         // [B,H]
    int T)
{
    const int tid = threadIdx.x;
    const int u   = tid & 31;            // hidden unit owned by this lane
    const int wl  = tid & 63;            // lane within the wave64
    const int b   = blockIdx.x * GPB + (tid >> 5);
    const int qp  = u & 3;               // quad position -> which 8-chunk we gather
    const int r   = u >> 3;              // readout row this lane contributes to
    const bool hi = ((u >> 2) & 1) != 0; // which half of our chunk for readout
    const bool writer = (u & 7) == 7;    // lane that stores logit row r

    // bpermute byte-indices for our 8-chunk: lane (groupbase + 8*qp + i)
    // (groupbase = 0 or 32 within the wave64; bpermute indexes the full wave)
    const int ib = ((wl & 32) + 8 * qp) << 2;
    const int idx0 = ib +  0, idx1 = ib +  4, idx2 = ib +  8, idx3 = ib + 12;
    const int idx4 = ib + 16, idx5 = ib + 20, idx6 = ib + 24, idx7 = ib + 28;

    // ---- persistent per-lane weights ----
    float whh[H];
#pragma unroll
    for (int k = 0; k < 8; ++k) {
        float4 w = *(const float4*)(W_hh + u * H + 4 * k);
        whh[4*k+0] = w.x; whh[4*k+1] = w.y; whh[4*k+2] = w.z; whh[4*k+3] = w.w;
    }
    const float wih0 = W_ih[u*5+0], wih1 = W_ih[u*5+1], wih2 = W_ih[u*5+2],
                wih3 = W_ih[u*5+3], wih4 = W_ih[u*5+4];
    const float bias = b_ih[u] + b_hh[u];
    const float4 wr4 = *(const float4*)(W_ro + r * H + qp * 8 + (hi ? 4 : 0));
    const float bro = b_ro[r];

    const float* oh_ptr = onehot  + (size_t)b * T * 4;
    const float* rw_ptr = rewards + (size_t)b * T;
    float*       lg_ptr = out_logits + (size_t)b * T * 4;

    // ---- 4-step-deep x prefetch ring ----
    float4 oh0 = *(const float4*)(oh_ptr + 0);
    float4 oh1 = *(const float4*)(oh_ptr + 4);
    float4 oh2 = *(const float4*)(oh_ptr + 8);
    float4 oh3 = *(const float4*)(oh_ptr + 12);
    float4 rw  = *(const float4*)(rw_ptr);

    float hj = 0.0f;                     // h^{(-1)} = 0
    float pA[8], pB[8];                  // double-buffered gathered chunk

    // logits_t from a gathered h^{(t)} chunk buffer
    auto readout = [&](const float (&p)[8], int t) {
        float s0 = hi ? p[4] : p[0];
        float s1 = hi ? p[5] : p[1];
        float s2 = hi ? p[6] : p[2];
        float s3 = hi ? p[7] : p[3];
        float s = fmaf(s3, wr4.w, fmaf(s2, wr4.z, fmaf(s1, wr4.y, s0 * wr4.x)));
        s += DPPMOV(s, ROW_SHR1);
        s += DPPMOV(s, ROW_SHR2);
        s += DPPMOV(s, ROW_SHR4);        // lane (8r+7) holds full dot of row r
        if (writer) lg_ptr[(size_t)t * 4 + r] = s + bro;
    };

    // register-level all-gather of h^{(t-1)} chunk via ds_bpermute (no LDS mem,
    // no write->read round trip); readout(pO) fills the bpermute latency.
    auto step = [&](float (&pN)[8], const float (&pO)[8], float xp, int t, bool ro) {
        const int hb = __float_as_int(hj);
        pN[0] = __int_as_float(__builtin_amdgcn_ds_bpermute(idx0, hb));
        pN[1] = __int_as_float(__builtin_amdgcn_ds_bpermute(idx1, hb));
        pN[2] = __int_as_float(__builtin_amdgcn_ds_bpermute(idx2, hb));
        pN[3] = __int_as_float(__builtin_amdgcn_ds_bpermute(idx3, hb));
        pN[4] = __int_as_float(__builtin_amdgcn_ds_bpermute(idx4, hb));
        pN[5] = __int_as_float(__builtin_amdgcn_ds_bpermute(idx5, hb));
        pN[6] = __int_as_float(__builtin_amdgcn_ds_bpermute(idx6, hb));
        pN[7] = __int_as_float(__builtin_amdgcn_ds_bpermute(idx7, hb));
        if (ro) readout(pO, t - 2);      // latency filler (depends only on pO)
        float a0 = xp, a1 = 0.f, a2 = 0.f, a3 = 0.f;
        CH8(a0, 0);
        CH8(a1, 1);
        CH8(a2, 2);
        CH8(a3, 3);
        hj = fast_tanh((a0 + a1) + (a2 + a3));
    };

#define XP(oh, rwc) fmaf((oh).x, wih0, fmaf((oh).y, wih1, fmaf((oh).z, wih2, \
                     fmaf((oh).w, wih3, fmaf((rwc), wih4, bias)))))

    // ---- peeled first block (t = 0..3): no readout for t<2 ----
    {
        float xp0 = XP(oh0, rw.x), xp1 = XP(oh1, rw.y),
              xp2 = XP(oh2, rw.z), xp3 = XP(oh3, rw.w);
        oh0 = *(const float4*)(oh_ptr + 16);
        oh1 = *(const float4*)(oh_ptr + 20);
        oh2 = *(const float4*)(oh_ptr + 24);
        oh3 = *(const float4*)(oh_ptr + 28);
        rw  = *(const float4*)(rw_ptr + 4);
        step(pA, pB, xp0, 0, false);
        step(pB, pA, xp1, 1, false);
        step(pA, pB, xp2, 2, true);
        step(pB, pA, xp3, 3, true);
    }

    for (int tb = 4; tb < T; tb += 4) {
        float xp0 = XP(oh0, rw.x), xp1 = XP(oh1, rw.y),
              xp2 = XP(oh2, rw.z), xp3 = XP(oh3, rw.w);
        if (tb + 4 < T) {
            oh0 = *(const float4*)(oh_ptr + (size_t)(tb + 4) * 4);
            oh1 = *(const float4*)(oh_ptr + (size_t)(tb + 5) * 4);
            oh2 = *(const float4*)(oh_ptr + (size_t)(tb + 6) * 4);
            oh3 = *(const float4*)(oh_ptr + (size_t)(tb + 7) * 4);
            rw  = *(const float4*)(rw_ptr + tb + 4);
        }
        step(pA, pB, xp0, tb + 0, true);
        step(pB, pA, xp1, tb + 1, true);
        step(pA, pB, xp2, tb + 2, true);
        step(pB, pA, xp3, tb + 3, true);
    }

    // ---- epilogue ----
    readout(pB, T - 2);                  // pB = h^{(T-2)} (gathered at t=T-1)
    {
        const int hb = __float_as_int(hj);   // hj = h^{(T-1)}
        pA[0] = __int_as_float(__builtin_amdgcn_ds_bpermute(idx0, hb));
        pA[1] = __int_as_float(__builtin_amdgcn_ds_bpermute(idx1, hb));
        pA[2] = __int_as_float(__builtin_amdgcn_ds_bpermute(idx2, hb));
        pA[3] = __int_as_float(__builtin_amdgcn_ds_bpermute(idx3, hb));
        pA[4] = __int_as_float(__builtin_amdgcn_ds_bpermute(idx4, hb));
        pA[5] = __int_as_float(__builtin_amdgcn_ds_bpermute(idx5, hb));
        pA[6] = __int_as_float(__builtin_amdgcn_ds_bpermute(idx6, hb));
        pA[7] = __int_as_float(__builtin_amdgcn_ds_bpermute(idx7, hb));
    }
    readout(pA, T - 1);                  // logits_{T-1} from h^{(T-1)}
    out_hT[(size_t)b * H + u] = hj;      // h_T
}

extern "C" void kernel_launch(void* const* d_in, const int* in_sizes, int n_in,
                              void* d_out, int out_size, void* d_ws, size_t ws_size,
                              hipStream_t stream) {
    const float* onehot  = (const float*)d_in[0];
    const float* rewards = (const float*)d_in[1];
    const float* W_ih    = (const float*)d_in[2];
    const float* W_hh    = (const float*)d_in[3];
    const float* b_ih    = (const float*)d_in[4];
    const float* b_hh    = (const float*)d_in[5];
    const float* W_ro    = (const float*)d_in[6];
    const float* b_ro    = (const float*)d_in[7];

    const int T = 1024;                  // per setup_inputs()
    const int B = in_sizes[1] / T;       // in_sizes[1] = B*T

    float* out_logits = (float*)d_out;                        // [B,T,4]
    float* out_hT     = (float*)d_out + (size_t)B * T * 4;    // [B,H]

    dim3 block(256);                     // 4 waves/block, 1024 waves total
    dim3 grid(B / GPB);                  // = 256 blocks -> 1 wave/SIMD chip-wide
    rnn_fused<<<grid, block, 0, stream>>>(onehot, rewards, W_ih, W_hh,
                                          b_ih, b_hh, W_ro, b_ro,
                                          out_logits, out_hT, T);
}